// Round 8
// baseline (83185.468 us; speedup 1.0000x reference)
//
#include <hip/hip_runtime.h>
#include <hip/hip_fp16.h>
#include <math.h>

// Persistent RK45 (Dormand-Prince, FSAL) integrator for
//   dy/dt = y * (r + A@y + eps@P[d(t)]),  n=4096, up to 512 adaptive steps.
// R8: communication-minimal decomposition. R5->R7 showed the exchange cost
// scales with the all-gather volume (NBLK x 16KB/stage through the uncached
// coherence point), not with poll traffic. So: 64 blocks x 1024 threads
// (ROWS=64, 4 cols/thread) -> per-stage k all-gather drops 4x to 1 MB, and
// only 64 CUs participate in the protocol. A stays in registers as fp16
// (64 rows x 4 cols = 128 VGPRs/thread, same budget as R7). Exchange =
// R5/R7-proven primitives only: relaxed agent atomics, s_waitcnt(0) between
// data stores and per-block tag store, wave-0 scan of 64 tags, direct data
// read after scan (store-ack => IF-visible, proven by R5/R7 passing).
// Err partials ride in a tagged side array read only at stage 7; every
// block reduces them in the same order -> identical accept decisions.

#define N        4096
#define NBLK     64
#define NTHR     1024
#define ROWS     64          // rows of A per block (NBLK*ROWS == N)
#define MAXSTEP  512
#define PERTS    8

typedef unsigned long long ull;

static_assert(NBLK * ROWS == N, "row partition");
static_assert(NTHR * 4 == N, "column partition (1 float4 per thread)");

__device__ __forceinline__ float4 ld4(const float* p){ return *reinterpret_cast<const float4*>(p); }
__device__ __forceinline__ void   st4(float* p, float4 v){ *reinterpret_cast<float4*>(p) = v; }

__global__ void __launch_bounds__(NTHR, 1)
mbpert_rk45_kernel(const float* __restrict__ x, const int* __restrict__ tptr,
                   const float* __restrict__ r, const float* __restrict__ A,
                   const float* __restrict__ eps, const float* __restrict__ Pm,
                   float* __restrict__ out, float* __restrict__ W, int Tm)
{
  __shared__ float khist[6][N];          // 96 KB k-history
  __shared__ float part_sm[ROWS * 17];   // matvec wave-partials, padded (17 coprime 32)
  __shared__ float ys_rows[ROWS];        // stage vector at our 64 row indices
  __shared__ float ysb_rows[ROWS];       // base vector at our 64 row indices
  __shared__ float r_sh[ROWS];
  __shared__ float eps_sh[ROWS * PERTS];
  __shared__ float P_sh[32 * PERTS];
  __shared__ float es_sh;

  const int tid = threadIdx.x;
  const int b   = blockIdx.x;
  const int rowbase = b * ROWS;
  const int lane = tid & 63;
  const int wv   = tid >> 6;             // 0..15

  ull*   tags  = reinterpret_cast<ull*>(W);            // [64]  per-block stage tags
  float* err_f = W + 128;                              // [64]  per-block err partials
  ull*   kx0u  = reinterpret_cast<ull*>(W + 1024);     // [N/2] exchange buf A (16 KB)
  ull*   kx1u  = reinterpret_cast<ull*>(W + 1024 + N); // [N/2] exchange buf B

  // ---- persistent LDS constants ----
  if (tid < ROWS)             r_sh[tid]     = r[rowbase + tid];
  if (tid < ROWS * PERTS)     eps_sh[tid]   = eps[rowbase * PERTS + tid];
  if (tid < (Tm + 1) * PERTS) P_sh[tid]     = Pm[tid];
  if (tid < ROWS)             ysb_rows[tid] = x[rowbase + tid];

  // ---- A fragment -> registers (fp16), once ----
  // Thread owns cols tid*4..tid*4+3 of rows rowbase..rowbase+63.
  __half2 Af[ROWS][2];
  {
    const float* Ac = A + (size_t)rowbase * N + tid * 4;
    #pragma unroll
    for (int rr = 0; rr < ROWS; rr++){
      float4 a = ld4(Ac + (size_t)rr * N);
      Af[rr][0] = __floats2half2_rn(a.x, a.y);
      Af[rr][1] = __floats2half2_rn(a.z, a.w);
    }
  }

  float4 ysbf = ld4(x + tid * 4);        // base vector fragment (4 cols)
  float4 ysf;                            // stage vector fragment
  __syncthreads();

  const float t_end = (float)(*tptr);
  const float Tf    = (float)Tm;
  float t = 0.0f;
  float h = t_end * 0.01f;
  unsigned gen = 0;

  // matvec from registers; returns row dot for wave-0 lane `lane` (row rowbase+lane)
  auto mv = [&]() -> float {
    float acc[ROWS];
    #pragma unroll
    for (int rr = 0; rr < ROWS; rr++){
      float2 lo = __half22float2(Af[rr][0]);
      float2 hi = __half22float2(Af[rr][1]);
      acc[rr] = fmaf(lo.x, ysf.x, fmaf(lo.y, ysf.y, fmaf(hi.x, ysf.z, fmaf(hi.y, ysf.w, 0.f))));
    }
    __syncthreads();                     // part_sm free from previous use
    #pragma unroll
    for (int rr = 0; rr < ROWS; rr++){
      float s = acc[rr];
      #pragma unroll
      for (int off = 32; off; off >>= 1) s += __shfl_xor(s, off, 64);
      if (lane == 0) part_sm[rr * 17 + wv] = s;
    }
    __syncthreads();
    float dot = 0.f;
    if (wv == 0){
      #pragma unroll
      for (int w = 0; w < 16; w++) dot += part_sm[lane * 17 + w];
    }
    return dot;
  };

  // k for row rowbase+lane (wave 0): y_s * (r + dot + eps@P[d])
  auto kval = [&](float dot, float ts) -> float {
    int d = (int)((Tf * ts) / 30.0f);
    d = d < 0 ? 0 : (d > Tm ? Tm : d);
    float ep = 0.f;
    #pragma unroll
    for (int p = 0; p < PERTS; p++) ep += eps_sh[lane * PERTS + p] * P_sh[d * PERTS + p];
    return ys_rows[lane] * (r_sh[lane] + dot + ep);
  };

  // ysf = ysbf + h * sum(cf[m] * khist[sli[m]]) over our 4 columns
  auto build = [&](const int* sli, const float* cf, int nk){
    const int c = tid * 4;
    float4 v = ysbf;
    for (int m = 0; m < nk; m++){
      float cc = h * cf[m];
      float4 kv = ld4(&khist[sli[m]][c]);
      v.x = fmaf(cc, kv.x, v.x); v.y = fmaf(cc, kv.y, v.y);
      v.z = fmaf(cc, kv.z, v.z); v.w = fmaf(cc, kv.w, v.w);
    }
    ysf = v;
    unsigned o = (unsigned)(c - rowbase);
    if (o < ROWS) st4(&ys_rows[o], v);
    __syncthreads();
  };

  // publish own 64 k's (+err partial), tag, scan 64 tags, pull 4096 k's
  auto exchange = [&](int slot, float kv, bool werr, float errv){
    ++gen;
    ull* kx = (gen & 1u) ? kx1u : kx0u;          // double buffer by parity
    if (wv == 0){
      float kvn = __shfl_down(kv, 1, 64);
      if ((lane & 1) == 0){
        union { float2 f; ull u; } cv;
        cv.f = make_float2(kv, kvn);
        __hip_atomic_store(&kx[(rowbase >> 1) + (lane >> 1)], cv.u,
                           __ATOMIC_RELAXED, __HIP_MEMORY_SCOPE_AGENT);
      }
      if (werr && lane == 0)
        __hip_atomic_store(&err_f[b], errv, __ATOMIC_RELAXED, __HIP_MEMORY_SCOPE_AGENT);
      __builtin_amdgcn_sched_barrier(0);
      __builtin_amdgcn_s_waitcnt(0);             // wave0's data stores at coherence point
      __builtin_amdgcn_sched_barrier(0);
      if (lane == 0)
        __hip_atomic_store(&tags[b], (ull)gen, __ATOMIC_RELAXED, __HIP_MEMORY_SCOPE_AGENT);
      for (;;){                                  // scan all 64 block tags (1/lane)
        ull tg = __hip_atomic_load(&tags[lane], __ATOMIC_RELAXED, __HIP_MEMORY_SCOPE_AGENT);
        if (__all(tg >= (ull)gen)) break;
        __builtin_amdgcn_s_sleep(2);
      }
      if (werr){                                 // err visible (stored before tags)
        float ev = __hip_atomic_load(&err_f[lane], __ATOMIC_RELAXED, __HIP_MEMORY_SCOPE_AGENT);
        #pragma unroll
        for (int off = 32; off; off >>= 1) ev += __shfl_xor(ev, off, 64);
        if (lane == 0) es_sh = ev;
      }
    }
    __syncthreads();
    union { float2 f; ull u; } a0, a1;           // 2 coalesced dwordx2 loads/thread
    a0.u = __hip_atomic_load(&kx[tid],        __ATOMIC_RELAXED, __HIP_MEMORY_SCOPE_AGENT);
    a1.u = __hip_atomic_load(&kx[NTHR + tid], __ATOMIC_RELAXED, __HIP_MEMORY_SCOPE_AGENT);
    float2* kh2 = reinterpret_cast<float2*>(&khist[slot][0]);
    kh2[tid] = a0.f; kh2[NTHR + tid] = a1.f;
    __syncthreads();
  };

  int sl[6] = {0, 1, 2, 3, 4, 5};      // logical k1..k6 -> physical LDS slots
  bool exhausted = true;

  for (int n = 0; n < MAXSTEP; ++n){
    if (n > 0){
      float es = es_sh;                          // set by last stage-7 exchange
      float enorm = sqrtf(es * (1.0f / (float)N));
      bool accept = (enorm <= 1.0f);
      if (accept){
        t += h;
        int tmp = sl[0]; sl[0] = sl[1]; sl[1] = tmp;  // FSAL: k1 <- k7 (in k2's slot)
        ysbf = ysf;
        if (tid < ROWS) ysb_rows[tid] = ys_rows[tid];
      }
      float fac = 0.9f * powf(enorm + 1e-10f, -0.2f);
      fac = fminf(fmaxf(fac, 0.2f), 10.0f);
      h *= fac;
      __syncthreads();
    }
    if (t >= t_end) { exhausted = false; break; }
    h = fminf(h, t_end - t);
    if (!(h > 0.0f)) { exhausted = false; break; }

    if (n == 0){
      // ---- stage 1 (once ever; FSAL covers later steps) ----
      ysf = ysbf;
      { unsigned o = (unsigned)(tid * 4 - rowbase);
        if (o < ROWS) st4(&ys_rows[o], ysf); }
      __syncthreads();
      float dot = mv();
      float kv = (wv == 0) ? kval(dot, t) : 0.f;
      exchange(sl[0], kv, false, 0.f);
    }

    // ---- stage 2 ----
    { const float cf[1] = {0.2f}; const int s_[1] = {sl[0]};
      build(s_, cf, 1);
      float dot = mv();
      float kv = (wv == 0) ? kval(dot, t + 0.2f * h) : 0.f;
      exchange(sl[1], kv, false, 0.f); }

    // ---- stage 3 ----
    { const float cf[2] = {3.f/40.f, 9.f/40.f}; const int s_[2] = {sl[0], sl[1]};
      build(s_, cf, 2);
      float dot = mv();
      float kv = (wv == 0) ? kval(dot, t + 0.3f * h) : 0.f;
      exchange(sl[2], kv, false, 0.f); }

    // ---- stage 4 ----
    { const float cf[3] = {44.f/45.f, -56.f/15.f, 32.f/9.f};
      const int s_[3] = {sl[0], sl[1], sl[2]};
      build(s_, cf, 3);
      float dot = mv();
      float kv = (wv == 0) ? kval(dot, t + 0.8f * h) : 0.f;
      exchange(sl[3], kv, false, 0.f); }

    // ---- stage 5 ----
    { const float cf[4] = {19372.f/6561.f, -25360.f/2187.f, 64448.f/6561.f, -212.f/729.f};
      const int s_[4] = {sl[0], sl[1], sl[2], sl[3]};
      build(s_, cf, 4);
      float dot = mv();
      float kv = (wv == 0) ? kval(dot, t + (8.f/9.f) * h) : 0.f;
      exchange(sl[4], kv, false, 0.f); }

    // ---- stage 6 ----
    { const float cf[5] = {9017.f/3168.f, -355.f/33.f, 46732.f/5247.f, 49.f/176.f, -5103.f/18656.f};
      const int s_[5] = {sl[0], sl[1], sl[2], sl[3], sl[4]};
      build(s_, cf, 5);
      float dot = mv();
      float kv = (wv == 0) ? kval(dot, t + h) : 0.f;
      exchange(sl[5], kv, false, 0.f); }

    // ---- stage 7: ys = y5 candidate; err partial; k7 -> sl[1] (k2 dead) ----
    { const float cf[5] = {35.f/384.f, 500.f/1113.f, 125.f/192.f, -2187.f/6784.f, 11.f/84.f};
      const int s_[5] = {sl[0], sl[2], sl[3], sl[4], sl[5]};
      build(s_, cf, 5);                // ysf/ys_rows = y5 candidate
      float dot = mv();
      float k7v = 0.f, errv = 0.f;
      if (wv == 0){
        k7v = kval(dot, t + h);
        int gi = rowbase + lane;
        float e = (71.f/57600.f)  * khist[sl[0]][gi] - (71.f/16695.f)    * khist[sl[2]][gi]
                + (71.f/1920.f)   * khist[sl[3]][gi] - (17253.f/339200.f)* khist[sl[4]][gi]
                + (22.f/525.f)    * khist[sl[5]][gi] - (1.f/40.f)        * k7v;
        e *= h;
        float sc = 1e-6f + 1e-3f * fmaxf(fabsf(ysb_rows[lane]), fabsf(ys_rows[lane]));
        float q = e / sc;
        float qq = q * q;                        // block partial: sum over 64 rows
        #pragma unroll
        for (int off = 32; off; off >>= 1) qq += __shfl_xor(qq, off, 64);
        errv = qq;
      }
      exchange(sl[1], k7v, true, errv);          // publish k7+err, fetch, es -> es_sh
    }
  }

  if (exhausted){
    // apply the final (iteration 511) accept decision, as the reference does
    float es = es_sh;
    bool accept = sqrtf(es * (1.0f / (float)N)) <= 1.0f;
    if (tid < ROWS) out[rowbase + tid] = accept ? ys_rows[tid] : ysb_rows[tid];
  } else {
    if (tid < ROWS) out[rowbase + tid] = ysb_rows[tid];
  }
}

extern "C" void kernel_launch(void* const* d_in, const int* in_sizes, int n_in,
                              void* d_out, int out_size, void* d_ws, size_t ws_size,
                              hipStream_t stream)
{
  const float* x   = (const float*)d_in[0];
  const int*   tp  = (const int*)  d_in[1];
  const float* r   = (const float*)d_in[2];
  const float* A   = (const float*)d_in[3];
  const float* eps = (const float*)d_in[4];
  const float* Pm  = (const float*)d_in[5];
  float* out = (float*)d_out;
  float* W   = (float*)d_ws;
  int Tm = in_sizes[5] / PERTS - 1;   // P rows - 1  (== 30)

  // zero tags + err partials (ws is re-poisoned to 0xAA before every call;
  // the `tags >= gen` scan would false-positive on poison)
  hipMemsetAsync(d_ws, 0, 1024, stream);
  mbpert_rk45_kernel<<<dim3(NBLK), dim3(NTHR), 0, stream>>>(
      x, tp, r, A, eps, Pm, out, W, Tm);
}